// Round 2
// baseline (16137.866 us; speedup 1.0000x reference)
//
#include <hip/hip_runtime.h>
#include <cstddef>

#define T_STEPS 1024
#define NB      64
#define DIN     128
#define HID     256
#define KTOT    384          // DIN + HID
#define NROW    1024         // 4*HID gate rows per dir

// per-WG geometry: 256 WGs = 16 groups (2 dir x 8 batch-tiles) x 16 j-slices
#define JT   16              // j-dims per WG
#define RWG  64              // gate rows per WG = 4*JT
#define BT   8               // batch rows per group
#define WPG  16              // WGs per group
#define NWG  256

// ws byte offsets
#define WG_OFF   0u          // bf16 weights [2][1024][384] ushort = 1,572,864 B
#define BIAS_OFF 1572864u    // float [2][1024] = 8,192 B
#define HG_OFF   1581056u    // float [2 parity][2 dir][64][256] = 262,144 B
#define BAR_OFF  1843200u    // uint [16 groups][1024 steps] = 65,536 B

#define OUT_MAIN (T_STEPS * NB * 2 * HID)
#define TAIL_H   OUT_MAIN
#define TAIL_C   (OUT_MAIN + 2 * NB * HID)

static __device__ __forceinline__ unsigned short f2bf(float f) {
  unsigned u = __float_as_uint(f);
  unsigned r = (u + 0x7fffu + ((u >> 16) & 1u)) >> 16;  // RNE
  return (unsigned short)r;
}

__global__ void prep_kernel(const float* __restrict__ Wih_f, const float* __restrict__ Whh_f,
                            const float* __restrict__ bih_f, const float* __restrict__ bhh_f,
                            const float* __restrict__ Wih_r, const float* __restrict__ Whh_r,
                            const float* __restrict__ bih_r, const float* __restrict__ bhh_r,
                            const float* __restrict__ hx,
                            unsigned short* __restrict__ Wg, float* __restrict__ bias4,
                            float* __restrict__ hg, unsigned* __restrict__ bar) {
  const int total = 786432 + 2048 + 32768 + 16384;
  for (int i = blockIdx.x * blockDim.x + threadIdx.x; i < total;
       i += gridDim.x * blockDim.x) {
    if (i < 786432) {
      int d = i / 393216;
      int r = i - d * 393216;
      int rowg = r / 384, k = r - rowg * 384;       // rowg = j*4+q (interleaved)
      int j = rowg >> 2, q = rowg & 3;
      int g = q * HID + j;                          // torch gate row
      const float* Wih = d ? Wih_r : Wih_f;
      const float* Whh = d ? Whh_r : Whh_f;
      float v = (k < DIN) ? Wih[g * DIN + k] : Whh[g * HID + (k - DIN)];
      Wg[i] = f2bf(v);
    } else if (i < 786432 + 2048) {
      int r = i - 786432;
      int d = r >> 10, rowg = r & 1023;
      int j = rowg >> 2, q = rowg & 3;
      int g = q * HID + j;
      bias4[r] = d ? (bih_r[g] + bhh_r[g]) : (bih_f[g] + bhh_f[g]);
    } else if (i < 786432 + 2048 + 32768) {
      int r = i - (786432 + 2048);
      hg[r] = hx[r];                                // parity 0 = hx [2][64][256]
    } else {
      bar[i - (786432 + 2048 + 32768)] = 0u;
    }
  }
}

// Persistent kernel: 256 WGs x 256 threads, all timesteps internal.
__global__ __launch_bounds__(256, 1) void lstm_persist(
    const float* __restrict__ x, const unsigned short* __restrict__ Wg,
    const float* __restrict__ bias4, const float* __restrict__ cx,
    float* __restrict__ hg, unsigned* __restrict__ bar,
    float* __restrict__ out) {
  __shared__ __align__(16) unsigned short wl[RWG][392];  // bf16, dword-stride 196 (%32==4)
  __shared__ __align__(16) float in_[BT][KTOT];          // [x | h], broadcast reads
  __shared__ float gl[RWG][9];                           // gates [row][b], pad 9

  const int tid   = threadIdx.x;
  const int wg    = blockIdx.x;
  const int grp   = wg >> 4;        // 0..15
  const int jsl   = wg & 15;        // j-slice in group
  const int d     = grp >> 3;
  const int btile = grp & 7;
  const int b0    = btile * BT;
  const int j0    = jsl * JT;

  // one-time: weights -> LDS (uint copies, contiguous per row)
  {
    const unsigned* src = (const unsigned*)(Wg + ((size_t)d * NROW + (size_t)jsl * RWG) * KTOT);
    unsigned* dst = (unsigned*)&wl[0][0];
    for (int iu = tid; iu < RWG * (KTOT / 2); iu += 256) {
      int r = iu / (KTOT / 2), ku = iu - r * (KTOT / 2);
      dst[r * 196 + ku] = src[r * (KTOT / 2) + ku];
    }
  }
  const int row = tid & 63;
  const int bp  = tid >> 6;
  const float brow = bias4[d * NROW + jsl * RWG + row];
  float c_reg = 0.f;
  if (tid < 128) {
    int jl = tid >> 3, bb = tid & 7;
    c_reg = cx[((size_t)d * NB + b0 + bb) * HID + j0 + jl];
  }
  __syncthreads();

  for (int s = 0; s < T_STEPS; ++s) {
    const int pr = s & 1, pw = pr ^ 1;
    const int t  = d ? (T_STEPS - 1 - s) : s;

    // stage x_t (plain, read-only) and h_prev (agent-coherent)
    for (int i = tid; i < BT * DIN; i += 256) {
      int bb = i >> 7, k = i & 127;
      in_[bb][k] = x[((size_t)t * NB + b0 + bb) * DIN + k];
    }
    {
      const float* hsrc = hg + (size_t)(pr * 2 + d) * NB * HID;
      for (int i = tid; i < BT * HID; i += 256) {
        int bb = i >> 8, j = i & 255;
        in_[bb][DIN + j] = __hip_atomic_load(hsrc + (size_t)(b0 + bb) * HID + j,
                                             __ATOMIC_RELAXED, __HIP_MEMORY_SCOPE_AGENT);
      }
    }
    __syncthreads();

    // GEMM: thread -> (gate row, batches bp and bp+4)
    float a0 = brow, a1 = brow;
    {
      const unsigned short* wr = &wl[row][0];
      const float* iA = &in_[bp][0];
      const float* iB = &in_[bp + 4][0];
#pragma unroll
      for (int k = 0; k < KTOT; k += 8) {
        uint4 wv = *(const uint4*)(wr + k);
        float4 a_0 = *(const float4*)(iA + k);
        float4 a_1 = *(const float4*)(iA + k + 4);
        float4 b_0 = *(const float4*)(iB + k);
        float4 b_1 = *(const float4*)(iB + k + 4);
        float w0 = __uint_as_float(wv.x << 16), w1 = __uint_as_float(wv.x & 0xffff0000u);
        float w2 = __uint_as_float(wv.y << 16), w3 = __uint_as_float(wv.y & 0xffff0000u);
        float w4 = __uint_as_float(wv.z << 16), w5 = __uint_as_float(wv.z & 0xffff0000u);
        float w6 = __uint_as_float(wv.w << 16), w7 = __uint_as_float(wv.w & 0xffff0000u);
        a0 = fmaf(w0, a_0.x, a0); a1 = fmaf(w0, b_0.x, a1);
        a0 = fmaf(w1, a_0.y, a0); a1 = fmaf(w1, b_0.y, a1);
        a0 = fmaf(w2, a_0.z, a0); a1 = fmaf(w2, b_0.z, a1);
        a0 = fmaf(w3, a_0.w, a0); a1 = fmaf(w3, b_0.w, a1);
        a0 = fmaf(w4, a_1.x, a0); a1 = fmaf(w4, b_1.x, a1);
        a0 = fmaf(w5, a_1.y, a0); a1 = fmaf(w5, b_1.y, a1);
        a0 = fmaf(w6, a_1.z, a0); a1 = fmaf(w6, b_1.z, a1);
        a0 = fmaf(w7, a_1.w, a0); a1 = fmaf(w7, b_1.w, a1);
      }
    }
    gl[row][bp]     = a0;
    gl[row][bp + 4] = a1;
    __syncthreads();

    if (tid < 128) {
      int jl = tid >> 3, bb = tid & 7;
      float gi = gl[jl * 4 + 0][bb];
      float gf = gl[jl * 4 + 1][bb];
      float gg = gl[jl * 4 + 2][bb];
      float go = gl[jl * 4 + 3][bb];
      float ii = 1.f / (1.f + __expf(-gi));
      float ff = 1.f / (1.f + __expf(-gf));
      float g2 = tanhf(gg);
      float oo = 1.f / (1.f + __expf(-go));
      float c = ff * c_reg + ii * g2;
      c_reg = c;
      float h = oo * tanhf(c);
      int b = b0 + bb, j = j0 + jl;
      __hip_atomic_store(hg + ((size_t)(pw * 2 + d) * NB + b) * HID + j, h,
                         __ATOMIC_RELAXED, __HIP_MEMORY_SCOPE_AGENT);
      out[((size_t)t * NB + b) * (2 * HID) + d * HID + j] = h;
      if (s == T_STEPS - 1) {
        out[TAIL_H + ((size_t)d * NB + b) * HID + j] = h;
        out[TAIL_C + ((size_t)d * NB + b) * HID + j] = c;
      }
    }
    __syncthreads();   // drains vmcnt -> h stores globally performed

    if (tid == 0) {
      unsigned* bpt = bar + grp * T_STEPS + s;
      __hip_atomic_fetch_add(bpt, 1u, __ATOMIC_RELEASE, __HIP_MEMORY_SCOPE_AGENT);
      while (__hip_atomic_load(bpt, __ATOMIC_ACQUIRE, __HIP_MEMORY_SCOPE_AGENT) < WPG) {
        __builtin_amdgcn_s_sleep(1);
      }
    }
    __syncthreads();
  }
}

extern "C" void kernel_launch(void* const* d_in, const int* in_sizes, int n_in,
                              void* d_out, int out_size, void* d_ws, size_t ws_size,
                              hipStream_t stream) {
  const float* x     = (const float*)d_in[0];
  const float* hx    = (const float*)d_in[1];
  const float* cx    = (const float*)d_in[2];
  const float* Wih_f = (const float*)d_in[3];
  const float* Whh_f = (const float*)d_in[4];
  const float* bih_f = (const float*)d_in[5];
  const float* bhh_f = (const float*)d_in[6];
  const float* Wih_r = (const float*)d_in[7];
  const float* Whh_r = (const float*)d_in[8];
  const float* bih_r = (const float*)d_in[9];
  const float* bhh_r = (const float*)d_in[10];
  float* out = (float*)d_out;

  unsigned short* Wg = (unsigned short*)((char*)d_ws + WG_OFF);
  float* bias4       = (float*)((char*)d_ws + BIAS_OFF);
  float* hg          = (float*)((char*)d_ws + HG_OFF);
  unsigned* bar      = (unsigned*)((char*)d_ws + BAR_OFF);

  hipLaunchKernelGGL(prep_kernel, dim3(1024), dim3(256), 0, stream,
                     Wih_f, Whh_f, bih_f, bhh_f, Wih_r, Whh_r, bih_r, bhh_r,
                     hx, Wg, bias4, hg, bar);
  hipLaunchKernelGGL(lstm_persist, dim3(NWG), dim3(256), 0, stream,
                     x, Wg, bias4, cx, hg, bar, out);
}

// Round 3
// 5588.888 us; speedup vs baseline: 2.8875x; 2.8875x over previous
//
#include <hip/hip_runtime.h>
#include <cstddef>

#define T_STEPS 1024
#define NB      64
#define DIN     128
#define HID     256
#define KTOT    384          // DIN + HID
#define NROW    1024         // 4*HID gate rows per dir

// 256 WGs = 16 groups (2 dir x 8 batch-tiles) x 16 j-slices
#define JT   16
#define RWG  64
#define BT   8
#define WPG  16
#define NWG  256

// ws byte offsets
#define WG_OFF   0u          // bf16 weights [2][1024][384] ushort
#define BIAS_OFF 1572864u    // float [2][1024]
#define HG_OFF   1581056u    // float [2 parity][2 dir][64][256]
#define BAR_OFF  1843200u    // uint [16 groups][1024 steps]

#define OUT_MAIN (T_STEPS * NB * 2 * HID)
#define TAIL_H   OUT_MAIN
#define TAIL_C   (OUT_MAIN + 2 * NB * HID)

static __device__ __forceinline__ unsigned short f2bf(float f) {
  unsigned u = __float_as_uint(f);
  unsigned r = (u + 0x7fffu + ((u >> 16) & 1u)) >> 16;  // RNE
  return (unsigned short)r;
}

__global__ void prep_kernel(const float* __restrict__ Wih_f, const float* __restrict__ Whh_f,
                            const float* __restrict__ bih_f, const float* __restrict__ bhh_f,
                            const float* __restrict__ Wih_r, const float* __restrict__ Whh_r,
                            const float* __restrict__ bih_r, const float* __restrict__ bhh_r,
                            const float* __restrict__ hx,
                            unsigned short* __restrict__ Wg, float* __restrict__ bias4,
                            float* __restrict__ hg, unsigned* __restrict__ bar) {
  const int total = 786432 + 2048 + 32768 + 16384;
  for (int i = blockIdx.x * blockDim.x + threadIdx.x; i < total;
       i += gridDim.x * blockDim.x) {
    if (i < 786432) {
      int d = i / 393216;
      int r = i - d * 393216;
      int rowg = r / 384, k = r - rowg * 384;   // rowg = j*4+q (interleaved)
      int j = rowg >> 2, q = rowg & 3;
      int g = q * HID + j;                      // torch gate row
      const float* Wih = d ? Wih_r : Wih_f;
      const float* Whh = d ? Whh_r : Whh_f;
      float v = (k < DIN) ? Wih[g * DIN + k] : Whh[g * HID + (k - DIN)];
      Wg[i] = f2bf(v);
    } else if (i < 786432 + 2048) {
      int r = i - 786432;
      int d = r >> 10, rowg = r & 1023;
      int j = rowg >> 2, q = rowg & 3;
      int g = q * HID + j;
      bias4[r] = d ? (bih_r[g] + bhh_r[g]) : (bih_f[g] + bhh_f[g]);
    } else if (i < 786432 + 2048 + 32768) {
      int r = i - (786432 + 2048);
      hg[r] = hx[r];                            // parity 0 = hx [2][64][256]
    } else {
      bar[i - (786432 + 2048 + 32768)] = 0u;
    }
  }
}

// 8-k inner block: 1 b128 weight read (bf16x8) + broadcast input reads, 16 FMA
#define GEMM8(kk) { \
    uint4 wv = *(const uint4*)(wr + (kk)); \
    float4 a_0 = *(const float4*)(iA + (kk)); \
    float4 a_1 = *(const float4*)(iA + (kk) + 4); \
    float4 b_0 = *(const float4*)(iB + (kk)); \
    float4 b_1 = *(const float4*)(iB + (kk) + 4); \
    float w0 = __uint_as_float(wv.x << 16), w1 = __uint_as_float(wv.x & 0xffff0000u); \
    float w2 = __uint_as_float(wv.y << 16), w3 = __uint_as_float(wv.y & 0xffff0000u); \
    float w4 = __uint_as_float(wv.z << 16), w5 = __uint_as_float(wv.z & 0xffff0000u); \
    float w6 = __uint_as_float(wv.w << 16), w7 = __uint_as_float(wv.w & 0xffff0000u); \
    a0 = fmaf(w0, a_0.x, a0); a1 = fmaf(w0, b_0.x, a1); \
    a0 = fmaf(w1, a_0.y, a0); a1 = fmaf(w1, b_0.y, a1); \
    a0 = fmaf(w2, a_0.z, a0); a1 = fmaf(w2, b_0.z, a1); \
    a0 = fmaf(w3, a_0.w, a0); a1 = fmaf(w3, b_0.w, a1); \
    a0 = fmaf(w4, a_1.x, a0); a1 = fmaf(w4, b_1.x, a1); \
    a0 = fmaf(w5, a_1.y, a0); a1 = fmaf(w5, b_1.y, a1); \
    a0 = fmaf(w6, a_1.z, a0); a1 = fmaf(w6, b_1.z, a1); \
    a0 = fmaf(w7, a_1.w, a0); a1 = fmaf(w7, b_1.w, a1); }

__global__ __launch_bounds__(256, 1) void lstm_persist(
    const float* __restrict__ x, const unsigned short* __restrict__ Wg,
    const float* __restrict__ bias4, const float* __restrict__ cx,
    float* __restrict__ hg, unsigned* __restrict__ bar,
    float* __restrict__ out) {
  __shared__ __align__(16) unsigned short wl[RWG][392];  // dword stride 196
  __shared__ __align__(16) float in_[BT][KTOT];
  __shared__ float gl[RWG][9];

  const int tid   = threadIdx.x;
  const int wg    = blockIdx.x;
  const int grp   = wg >> 4;
  const int jsl   = wg & 15;
  const int d     = grp >> 3;
  const int btile = grp & 7;
  const int b0    = btile * BT;
  const int j0    = jsl * JT;

  // one-time: weights -> LDS
  {
    const unsigned* src = (const unsigned*)(Wg + ((size_t)d * NROW + (size_t)jsl * RWG) * KTOT);
    unsigned* dst = (unsigned*)&wl[0][0];
    for (int iu = tid; iu < RWG * (KTOT / 2); iu += 256) {
      int r = iu / (KTOT / 2), ku = iu - r * (KTOT / 2);
      dst[r * 196 + ku] = src[r * (KTOT / 2) + ku];
    }
  }
  const int row = tid & 63;
  const int bp  = tid >> 6;
  const float brow = bias4[d * NROW + jsl * RWG + row];
  float c_reg = 0.f;
  if (tid < 128) {
    int jl = tid >> 3, bb = tid & 7;
    c_reg = cx[((size_t)d * NB + b0 + bb) * HID + j0 + jl];
  }
  // stage x(0): thread -> one float4
  {
    int t0 = d ? (T_STEPS - 1) : 0;
    int bb = tid >> 5, k = (tid & 31) * 4;
    *(float4*)&in_[bb][k] = *(const float4*)&x[((size_t)t0 * NB + b0 + bb) * DIN + k];
  }
  __syncthreads();
  // issue h(init) loads (parity 0), LLC-coherent, latency hidden under x-GEMM
  float h_tmp[8];
  {
    const float* hsrc = hg + ((size_t)d * NB + b0) * HID;
#pragma unroll
    for (int u = 0; u < 8; ++u)
      h_tmp[u] = __hip_atomic_load(hsrc + u * HID + tid,
                                   __ATOMIC_RELAXED, __HIP_MEMORY_SCOPE_AGENT);
  }

  for (int s = 0; s < T_STEPS; ++s) {
    const int pw = (s & 1) ^ 1;
    const int t  = d ? (T_STEPS - 1 - s) : s;

    float a0 = brow, a1 = brow;
    const unsigned short* wr = &wl[row][0];
    const float* iA = &in_[bp][0];
    const float* iB = &in_[bp + 4][0];
    // x-part GEMM (k < 128) — overlaps in-flight h loads
#pragma unroll
    for (int k = 0; k < DIN; k += 8) GEMM8(k)
    // park h(s-1) into LDS (first use of h_tmp -> compiler waits vmcnt here)
#pragma unroll
    for (int u = 0; u < 8; ++u) in_[u][DIN + tid] = h_tmp[u];
    __syncthreads();
    // h-part GEMM (k = 128..383)
#pragma unroll
    for (int k = DIN; k < KTOT; k += 8) GEMM8(k)
    gl[row][bp]     = a0;
    gl[row][bp + 4] = a1;
    __syncthreads();

    if (tid < 128) {
      int jl = tid >> 3, bb = tid & 7;
      float gi = gl[jl * 4 + 0][bb];
      float gf = gl[jl * 4 + 1][bb];
      float gg = gl[jl * 4 + 2][bb];
      float go = gl[jl * 4 + 3][bb];
      float ii = 1.f / (1.f + __expf(-gi));
      float ff = 1.f / (1.f + __expf(-gf));
      float g2 = tanhf(gg);
      float oo = 1.f / (1.f + __expf(-go));
      float c = ff * c_reg + ii * g2;
      c_reg = c;
      float h = oo * tanhf(c);
      int b = b0 + bb, j = j0 + jl;
      __hip_atomic_store(hg + ((size_t)(pw * 2 + d) * NB + b) * HID + j, h,
                         __ATOMIC_RELAXED, __HIP_MEMORY_SCOPE_AGENT);
      out[((size_t)t * NB + b) * (2 * HID) + d * HID + j] = h;
      if (s == T_STEPS - 1) {
        out[TAIL_H + ((size_t)d * NB + b) * HID + j] = h;
        out[TAIL_C + ((size_t)d * NB + b) * HID + j] = c;
      }
    }
    __syncthreads();   // drains vmcnt in every wave -> h at LLC before flag

    if (s < T_STEPS - 1) {
      unsigned* bpt = bar + grp * T_STEPS + s;
      if (tid == 0)
        __hip_atomic_fetch_add(bpt, 1u, __ATOMIC_RELAXED, __HIP_MEMORY_SCOPE_AGENT);
      // stage x(s+1) while waiting for group peers
      {
        int tn = d ? (T_STEPS - 2 - s) : (s + 1);
        int bb = tid >> 5, k = (tid & 31) * 4;
        *(float4*)&in_[bb][k] = *(const float4*)&x[((size_t)tn * NB + b0 + bb) * DIN + k];
      }
      if (tid == 0) {
        while (__hip_atomic_load(bpt, __ATOMIC_RELAXED, __HIP_MEMORY_SCOPE_AGENT) < WPG)
          __builtin_amdgcn_s_sleep(1);
      }
      __syncthreads();
      // issue next h loads (parity pw) — consumed at next iteration's park
      const float* hsrc = hg + ((size_t)(pw * 2 + d) * NB + b0) * HID;
#pragma unroll
      for (int u = 0; u < 8; ++u)
        h_tmp[u] = __hip_atomic_load(hsrc + u * HID + tid,
                                     __ATOMIC_RELAXED, __HIP_MEMORY_SCOPE_AGENT);
    }
  }
}

extern "C" void kernel_launch(void* const* d_in, const int* in_sizes, int n_in,
                              void* d_out, int out_size, void* d_ws, size_t ws_size,
                              hipStream_t stream) {
  const float* x     = (const float*)d_in[0];
  const float* hx    = (const float*)d_in[1];
  const float* cx    = (const float*)d_in[2];
  const float* Wih_f = (const float*)d_in[3];
  const float* Whh_f = (const float*)d_in[4];
  const float* bih_f = (const float*)d_in[5];
  const float* bhh_f = (const float*)d_in[6];
  const float* Wih_r = (const float*)d_in[7];
  const float* Whh_r = (const float*)d_in[8];
  const float* bih_r = (const float*)d_in[9];
  const float* bhh_r = (const float*)d_in[10];
  float* out = (float*)d_out;

  unsigned short* Wg = (unsigned short*)((char*)d_ws + WG_OFF);
  float* bias4       = (float*)((char*)d_ws + BIAS_OFF);
  float* hg          = (float*)((char*)d_ws + HG_OFF);
  unsigned* bar      = (unsigned*)((char*)d_ws + BAR_OFF);

  hipLaunchKernelGGL(prep_kernel, dim3(1024), dim3(256), 0, stream,
                     Wih_f, Whh_f, bih_f, bhh_f, Wih_r, Whh_r, bih_r, bhh_r,
                     hx, Wg, bias4, hg, bar);
  hipLaunchKernelGGL(lstm_persist, dim3(NWG), dim3(256), 0, stream,
                     x, Wg, bias4, cx, hg, bar, out);
}

// Round 4
// 2282.570 us; speedup vs baseline: 7.0700x; 2.4485x over previous
//
#include <hip/hip_runtime.h>
#include <cstddef>

#define T_STEPS 1024
#define NB      64
#define DIN     128
#define HID     256
#define WPG     16
#define NWG     256

typedef unsigned short u16;
typedef __attribute__((ext_vector_type(8))) short short8;
typedef __attribute__((ext_vector_type(4))) float f32x4;

// ws byte offsets
#define WG_OFF   0u          // bf16 weights [2][1024 rows j*4+q][384 k]
#define BIAS_OFF 1572864u    // float [2][1024]
#define XB_OFF   1581056u    // bf16 x [1024][64][128]
#define HG_OFF   18358272u   // u16 h planes [parity][dir][hi/lo][64][256]
#define BAR_OFF  18620416u   // uint [16 groups][1024 steps]

#define OUT_MAIN (T_STEPS * NB * 2 * HID)
#define TAIL_H   OUT_MAIN
#define TAIL_C   (OUT_MAIN + 2 * NB * HID)

__device__ __forceinline__ u16 f2bf(float f) {
  unsigned u = __float_as_uint(f);
  return (u16)((u + 0x7fffu + ((u >> 16) & 1u)) >> 16);  // RNE
}
__device__ __forceinline__ float bf2f(u16 h) {
  return __uint_as_float(((unsigned)h) << 16);
}
__device__ __forceinline__ float sigm(float v) { return 1.f / (1.f + __expf(-v)); }
__device__ __forceinline__ float tanh_fast(float x) {
  float e = __expf(-2.f * fabsf(x));
  float r = (1.f - e) / (1.f + e);
  return x < 0.f ? -r : r;
}

__global__ void prep_kernel(const float* __restrict__ x,
                            const float* __restrict__ Wih_f, const float* __restrict__ Whh_f,
                            const float* __restrict__ bih_f, const float* __restrict__ bhh_f,
                            const float* __restrict__ Wih_r, const float* __restrict__ Whh_r,
                            const float* __restrict__ bih_r, const float* __restrict__ bhh_r,
                            const float* __restrict__ hx,
                            u16* __restrict__ Wg, float* __restrict__ bias4,
                            u16* __restrict__ xb, u16* __restrict__ hg,
                            unsigned* __restrict__ bar) {
  // segments: W 786432 | bias 2048 | xb 8388608 | hg 32768 | bar 16384
  const int total = 786432 + 2048 + 8388608 + 32768 + 16384;
  for (int i = blockIdx.x * blockDim.x + threadIdx.x; i < total;
       i += gridDim.x * blockDim.x) {
    if (i < 786432) {
      int d = i / 393216;
      int r = i - d * 393216;
      int rowg = r / 384, k = r - rowg * 384;   // rowg = j*4+q interleaved
      int j = rowg >> 2, q = rowg & 3;
      int g = q * HID + j;                      // torch gate row
      const float* Wih = d ? Wih_r : Wih_f;
      const float* Whh = d ? Whh_r : Whh_f;
      float v = (k < DIN) ? Wih[g * DIN + k] : Whh[g * HID + (k - DIN)];
      Wg[i] = f2bf(v);
    } else if (i < 786432 + 2048) {
      int r = i - 786432;
      int d = r >> 10, rowg = r & 1023;
      int j = rowg >> 2, q = rowg & 3;
      int g = q * HID + j;
      bias4[r] = d ? (bih_r[g] + bhh_r[g]) : (bih_f[g] + bhh_f[g]);
    } else if (i < 786432 + 2048 + 8388608) {
      int r = i - (786432 + 2048);
      xb[r] = f2bf(x[r]);                       // same [t][b][k] layout
    } else if (i < 786432 + 2048 + 8388608 + 32768) {
      int r = i - (786432 + 2048 + 8388608);
      int d = r >> 14, rem = r & 16383;
      float v = hx[r];
      u16 hi = f2bf(v);
      u16 lo = f2bf(v - bf2f(hi));
      hg[(d * 2 + 0) * 16384 + rem] = hi;       // parity 0 planes
      hg[(d * 2 + 1) * 16384 + rem] = lo;
    } else {
      bar[i - (786432 + 2048 + 8388608 + 32768)] = 0u;
    }
  }
}

// Persistent: 256 WGs x 256 thr. grp = wg>>4 (d=grp>>3, btile=grp&7), jsl = wg&15.
// Per WG: 64 gate rows (j0=jsl*16), 8 batches. Wave w owns n-tile rows [w*16,w*16+16).
// MFMA 16x16x32 bf16: D[m=batch][n=gaterow]; A rows 8..15 zeroed.
__global__ __launch_bounds__(256, 1) void lstm_persist(
    const u16* __restrict__ Wg, const float* __restrict__ bias4,
    const u16* __restrict__ xb, const float* __restrict__ cx,
    u16* __restrict__ hg, unsigned* __restrict__ bar,
    float* __restrict__ out) {
  extern __shared__ char smem[];
  u16* wl   = (u16*)smem;                // [64][392] weights bf16
  u16* inb  = (u16*)(smem + 50176);      // [16][648]: x(128) | h_hi(256) | h_lo(256) | pad
  float* gl = (float*)(smem + 70912);    // [64][13] gate pre-activations

  const int tid = threadIdx.x;
  const int wg  = blockIdx.x;
  const int grp = wg >> 4, jsl = wg & 15;
  const int d = grp >> 3, btile = grp & 7;
  const int b0 = btile * 8;
  const int j0 = jsl * 16;

  // one-time: weights -> LDS
  {
    const unsigned* src = (const unsigned*)(Wg + ((size_t)(d * 1024 + jsl * 64)) * 384);
    unsigned* dst = (unsigned*)wl;
    for (int iu = tid; iu < 64 * 192; iu += 256) {
      int r = iu / 192, c = iu - r * 192;
      dst[r * 196 + c] = src[r * 192 + c];
    }
  }
  // zero A rows 8..15 (dw 2592..5184)
  {
    unsigned* z = (unsigned*)inb;
    for (int i = tid; i < 2592; i += 256) z[2592 + i] = 0u;
  }
  // elementwise thread state (tid<64): bb=tid>>3 batch, jp=tid&7 -> j = 2jp,2jp+1
  const int bb = tid >> 3, jp = tid & 7;
  float bias8[8], c0 = 0.f, c1 = 0.f;
  if (tid < 64) {
#pragma unroll
    for (int e = 0; e < 2; ++e)
#pragma unroll
      for (int q = 0; q < 4; ++q)
        bias8[e * 4 + q] = bias4[d * 1024 + jsl * 64 + (2 * jp + e) * 4 + q];
    c0 = cx[((size_t)d * NB + b0 + bb) * HID + j0 + 2 * jp];
    c1 = cx[((size_t)d * NB + b0 + bb) * HID + j0 + 2 * jp + 1];
  }
  // stage x(t0)
  {
    int t0 = d ? (T_STEPS - 1) : 0;
    int xr = tid >> 5, k0 = (tid & 31) * 4;
    uint2 xv = *(const uint2*)(xb + ((size_t)t0 * NB + b0 + xr) * DIN + k0);
    *(uint2*)(inb + xr * 648 + k0) = xv;
  }
  __syncthreads();
  // issue h(parity 0) loads
  const int hb = tid >> 5, hj0 = (tid & 31) * 8;
  unsigned long long hh0, hh1, ll0, ll1;
  {
    const u16* hp = hg + (size_t)((0 * 2 + d) * 2 + 0) * 16384 + (size_t)(b0 + hb) * 256 + hj0;
    hh0 = __hip_atomic_load((const unsigned long long*)hp, __ATOMIC_RELAXED, __HIP_MEMORY_SCOPE_AGENT);
    hh1 = __hip_atomic_load((const unsigned long long*)(hp + 4), __ATOMIC_RELAXED, __HIP_MEMORY_SCOPE_AGENT);
    ll0 = __hip_atomic_load((const unsigned long long*)(hp + 16384), __ATOMIC_RELAXED, __HIP_MEMORY_SCOPE_AGENT);
    ll1 = __hip_atomic_load((const unsigned long long*)(hp + 16388), __ATOMIC_RELAXED, __HIP_MEMORY_SCOPE_AGENT);
  }

  const int l = tid & 63, w = tid >> 6;
  const u16* wrow = wl + (size_t)(w * 16 + (l & 15)) * 392 + ((l >> 4) * 8);
  const u16* arow = inb + (size_t)(l & 15) * 648 + ((l >> 4) * 8);
  const int glw = (w * 16 + (l & 15)) * 13 + ((l >> 4) * 4);

  for (int s = 0; s < T_STEPS; ++s) {
    const int pw = (s & 1) ^ 1;
    const int t = d ? (T_STEPS - 1 - s) : s;
    f32x4 acc0 = {0.f, 0.f, 0.f, 0.f}, acc1 = {0.f, 0.f, 0.f, 0.f};
    // x-part MFMA (k blocks 0..3) — overlaps in-flight h loads
#pragma unroll
    for (int kb = 0; kb < 4; ++kb) {
      short8 B = *(const short8*)(wrow + kb * 32);
      short8 A = *(const short8*)(arow + kb * 32);
      if (kb & 1) acc1 = __builtin_amdgcn_mfma_f32_16x16x32_bf16(A, B, acc1, 0, 0, 0);
      else        acc0 = __builtin_amdgcn_mfma_f32_16x16x32_bf16(A, B, acc0, 0, 0, 0);
    }
    // park h hi/lo into LDS (waits vmcnt on h regs)
    {
      uint4 hv; hv.x=(unsigned)hh0; hv.y=(unsigned)(hh0>>32); hv.z=(unsigned)hh1; hv.w=(unsigned)(hh1>>32);
      uint4 lv; lv.x=(unsigned)ll0; lv.y=(unsigned)(ll0>>32); lv.z=(unsigned)ll1; lv.w=(unsigned)(ll1>>32);
      *(uint4*)(inb + hb * 648 + 128 + hj0) = hv;
      *(uint4*)(inb + hb * 648 + 384 + hj0) = lv;
    }
    __syncthreads();
    // h-part MFMA: hi and lo share the same B fragment
#pragma unroll
    for (int jb = 0; jb < 8; ++jb) {
      short8 B  = *(const short8*)(wrow + 128 + jb * 32);
      short8 Ah = *(const short8*)(arow + 128 + jb * 32);
      short8 Al = *(const short8*)(arow + 384 + jb * 32);
      acc0 = __builtin_amdgcn_mfma_f32_16x16x32_bf16(Ah, B, acc0, 0, 0, 0);
      acc1 = __builtin_amdgcn_mfma_f32_16x16x32_bf16(Al, B, acc1, 0, 0, 0);
    }
    if (l < 32) {
      f32x4 a = acc0 + acc1;
      gl[glw + 0] = a[0]; gl[glw + 1] = a[1]; gl[glw + 2] = a[2]; gl[glw + 3] = a[3];
    }
    __syncthreads();
    if (tid < 64) {
      float g[8];
#pragma unroll
      for (int e = 0; e < 2; ++e)
#pragma unroll
        for (int q = 0; q < 4; ++q)
          g[e * 4 + q] = gl[((2 * jp + e) * 4 + q) * 13 + bb] + bias8[e * 4 + q];
      float i0 = sigm(g[0]), f0 = sigm(g[1]), gg0 = tanh_fast(g[2]), o0 = sigm(g[3]);
      c0 = f0 * c0 + i0 * gg0;
      float h0f = o0 * tanh_fast(c0);
      float i1 = sigm(g[4]), f1 = sigm(g[5]), gg1 = tanh_fast(g[6]), o1 = sigm(g[7]);
      c1 = f1 * c1 + i1 * gg1;
      float h1f = o1 * tanh_fast(c1);
      u16 h0h = f2bf(h0f); u16 h0l = f2bf(h0f - bf2f(h0h));
      u16 h1h = f2bf(h1f); u16 h1l = f2bf(h1f - bf2f(h1h));
      unsigned hpair = (unsigned)h0h | ((unsigned)h1h << 16);
      unsigned lpair = (unsigned)h0l | ((unsigned)h1l << 16);
      u16* hp = hg + (size_t)((pw * 2 + d) * 2 + 0) * 16384 + (size_t)(b0 + bb) * 256 + j0 + 2 * jp;
      __hip_atomic_store((unsigned*)hp, hpair, __ATOMIC_RELAXED, __HIP_MEMORY_SCOPE_AGENT);
      __hip_atomic_store((unsigned*)(hp + 16384), lpair, __ATOMIC_RELAXED, __HIP_MEMORY_SCOPE_AGENT);
      float2 ho; ho.x = h0f; ho.y = h1f;
      *(float2*)(out + ((size_t)t * NB + b0 + bb) * (2 * HID) + d * HID + j0 + 2 * jp) = ho;
      if (s == T_STEPS - 1) {
        *(float2*)(out + TAIL_H + ((size_t)d * NB + b0 + bb) * HID + j0 + 2 * jp) = ho;
        float2 co; co.x = c0; co.y = c1;
        *(float2*)(out + TAIL_C + ((size_t)d * NB + b0 + bb) * HID + j0 + 2 * jp) = co;
      }
    }
    __syncthreads();   // drains vmcnt -> h stores at LLC before flag
    if (s == T_STEPS - 1) break;

    unsigned* bpt = bar + grp * T_STEPS + s;
    if (tid == 0)
      __hip_atomic_fetch_add(bpt, 1u, __ATOMIC_RELAXED, __HIP_MEMORY_SCOPE_AGENT);
    // stage x(s+1) while peers finish
    {
      int tn = d ? (T_STEPS - 2 - s) : (s + 1);
      int xr = tid >> 5, k0 = (tid & 31) * 4;
      uint2 xv = *(const uint2*)(xb + ((size_t)tn * NB + b0 + xr) * DIN + k0);
      *(uint2*)(inb + xr * 648 + k0) = xv;
    }
    if (tid == 0) {
      while (__hip_atomic_load(bpt, __ATOMIC_RELAXED, __HIP_MEMORY_SCOPE_AGENT) < WPG)
        __builtin_amdgcn_s_sleep(1);
    }
    __syncthreads();
    // issue h(s+1) loads (parity pw) — consumed at next iteration's park
    {
      const u16* hp = hg + (size_t)((pw * 2 + d) * 2 + 0) * 16384 + (size_t)(b0 + hb) * 256 + hj0;
      hh0 = __hip_atomic_load((const unsigned long long*)hp, __ATOMIC_RELAXED, __HIP_MEMORY_SCOPE_AGENT);
      hh1 = __hip_atomic_load((const unsigned long long*)(hp + 4), __ATOMIC_RELAXED, __HIP_MEMORY_SCOPE_AGENT);
      ll0 = __hip_atomic_load((const unsigned long long*)(hp + 16384), __ATOMIC_RELAXED, __HIP_MEMORY_SCOPE_AGENT);
      ll1 = __hip_atomic_load((const unsigned long long*)(hp + 16388), __ATOMIC_RELAXED, __HIP_MEMORY_SCOPE_AGENT);
    }
  }
}

extern "C" void kernel_launch(void* const* d_in, const int* in_sizes, int n_in,
                              void* d_out, int out_size, void* d_ws, size_t ws_size,
                              hipStream_t stream) {
  const float* x     = (const float*)d_in[0];
  const float* hx    = (const float*)d_in[1];
  const float* cx    = (const float*)d_in[2];
  const float* Wih_f = (const float*)d_in[3];
  const float* Whh_f = (const float*)d_in[4];
  const float* bih_f = (const float*)d_in[5];
  const float* bhh_f = (const float*)d_in[6];
  const float* Wih_r = (const float*)d_in[7];
  const float* Whh_r = (const float*)d_in[8];
  const float* bih_r = (const float*)d_in[9];
  const float* bhh_r = (const float*)d_in[10];
  float* out = (float*)d_out;

  u16* Wg       = (u16*)((char*)d_ws + WG_OFF);
  float* bias4  = (float*)((char*)d_ws + BIAS_OFF);
  u16* xb       = (u16*)((char*)d_ws + XB_OFF);
  u16* hg       = (u16*)((char*)d_ws + HG_OFF);
  unsigned* bar = (unsigned*)((char*)d_ws + BAR_OFF);

  hipFuncSetAttribute((const void*)lstm_persist,
                      hipFuncAttributeMaxDynamicSharedMemorySize, 74240);

  hipLaunchKernelGGL(prep_kernel, dim3(2048), dim3(256), 0, stream,
                     x, Wih_f, Whh_f, bih_f, bhh_f, Wih_r, Whh_r, bih_r, bhh_r,
                     hx, Wg, bias4, xb, hg, bar);
  hipLaunchKernelGGL(lstm_persist, dim3(NWG), dim3(256), 74240, stream,
                     Wg, bias4, xb, cx, hg, bar, out);
}